// Round 16
// baseline (215.053 us; speedup 1.0000x reference)
//
#include <hip/hip_runtime.h>
#include <hip/hip_bf16.h>

#define B_SZ 8192
#define IH   2048
#define H_SZ 1024
#define BM   256            // rows per block
#define BK   32             // K per tile
#define NKT  (IH / BK)      // 64 K-tiles

typedef __attribute__((ext_vector_type(8)))  short  short8;
typedef __attribute__((ext_vector_type(16))) float  floatx16;

static __device__ __forceinline__ ushort f2bf(float f) {
  union { float f; unsigned u; } v; v.f = f;
  unsigned u = v.u;
  u += 0x7fffu + ((u >> 16) & 1u);   // RNE
  return (ushort)(u >> 16);
}
static __device__ __forceinline__ float sigmoidf_(float x) {
  return 1.0f / (1.0f + __expf(-x));
}
static __device__ __forceinline__ float tanhf_(float x) {
  float ax = fabsf(x);
  float e = __expf(-2.0f * ax);
  float t = (1.0f - e) / (1.0f + e);
  return copysignf(t, x);
}

// ---------------------------------------------------------------------------
// Pre-pass 1: W[k][n] fp32 -> Wt2 k-chunk-major bf16:
//   slot (gck, gate, n) at ushort offset ((gck*4 + gate)*1024 + n)*8
// ---------------------------------------------------------------------------
__global__ __launch_bounds__(256) void convert_w2_kernel(
    const float* __restrict__ Wf, const float* __restrict__ Wi,
    const float* __restrict__ Wo, const float* __restrict__ Wc,
    ushort* __restrict__ Wt2) {
  __shared__ float tile[64][65];
  const int g  = blockIdx.z;
  const float* W = (g == 0) ? Wf : (g == 1) ? Wi : (g == 2) ? Wo : Wc;
  const int n0 = blockIdx.x * 64;
  const int k0 = blockIdx.y * 64;
  const int tid = threadIdx.x;
#pragma unroll
  for (int i = 0; i < 4; ++i) {
    int c = i * 256 + tid;
    int r = c >> 4, c4 = c & 15;
    float4 v = *(const float4*)(W + (size_t)(k0 + r) * H_SZ + n0 + c4 * 4);
    tile[r][c4 * 4 + 0] = v.x;
    tile[r][c4 * 4 + 1] = v.y;
    tile[r][c4 * 4 + 2] = v.z;
    tile[r][c4 * 4 + 3] = v.w;
  }
  __syncthreads();
#pragma unroll
  for (int i = 0; i < 2; ++i) {
    int u  = i * 256 + tid;
    int kc = u >> 6;          // 0..7
    int n  = u & 63;
    ushort o[8] __attribute__((aligned(16)));
#pragma unroll
    for (int e = 0; e < 8; ++e) o[e] = f2bf(tile[kc * 8 + e][n]);
    ushort* dst = Wt2 + (((size_t)(k0 / 8 + kc) * 4 + g) * 1024 + n0 + n) * 8;
    *(uint4*)dst = *(uint4*)&o[0];
  }
}

// ---------------------------------------------------------------------------
// Pre-pass 2: A = [x | h_prev] fp32 -> Abf2 k-chunk-major bf16:
//   slot (gck, row) at ushort offset (gck*8192 + row)*8
// ---------------------------------------------------------------------------
__global__ __launch_bounds__(256) void convert_a2_kernel(
    const float* __restrict__ x, const float* __restrict__ hp,
    ushort* __restrict__ Abf2) {
  __shared__ float tile[64][65];
  const int k0 = blockIdx.x * 64;
  const int r0 = blockIdx.y * 64;
  const int tid = threadIdx.x;
  const float* base = (k0 < 1024) ? x : hp;
  const int koff = (k0 < 1024) ? k0 : (k0 - 1024);
#pragma unroll
  for (int i = 0; i < 4; ++i) {
    int c = i * 256 + tid;
    int r = c >> 4, c4 = c & 15;
    float4 v = *(const float4*)(base + (size_t)(r0 + r) * 1024 + koff + c4 * 4);
    tile[r][c4 * 4 + 0] = v.x;
    tile[r][c4 * 4 + 1] = v.y;
    tile[r][c4 * 4 + 2] = v.z;
    tile[r][c4 * 4 + 3] = v.w;
  }
  __syncthreads();
#pragma unroll
  for (int i = 0; i < 2; ++i) {
    int u  = i * 256 + tid;
    int kc = u >> 6;
    int r  = u & 63;
    ushort o[8] __attribute__((aligned(16)));
#pragma unroll
    for (int e = 0; e < 8; ++e) o[e] = f2bf(tile[r][kc * 8 + e]);
    ushort* dst = Abf2 + ((size_t)(k0 / 8 + kc) * 8192 + r0 + r) * 8;
    *(uint4*)dst = *(uint4*)&o[0];
  }
}

// ---------------------------------------------------------------------------
// Fused 4-gate GEMM + LSTM epilogue — ZERO-LDS, ZERO-BARRIER free-running
// waves. Both operands load DIRECT from k-chunk-major global buffers into
// ping-pong register sets; no __shared__, no s_barrier, no explicit waits —
// the compiler's counted vmcnt before each MFMA operand use is the only
// synchronization. Waves drift independently; when one stalls on VMEM the
// co-resident wave issues MFMA (m114 TLP overlap) — removes the barrier
// lockstep that made all prior variants serialize pipe time (sum not max).
//
// Geometry: block 256 rows x 256 fused cols; 8 waves = 4M x 2N; wave
// 64 x 128 = 2 mt x 4 gates; acc[2][4] f32x16; 16 mfma_32x32x16/tile/wave.
// A frag: lane (row = b0+wm*64+mt*32+(ln&31), chunk 2ks+(ln>>5)) —
//   512 B contiguous per half-wave (coalesced).
// W frag: lane (col = n0g+wn*32+(ln&31), chunk 2ks+(ln>>5), gate g) —
//   512 B contiguous per half-wave; 16 KiB unique per tile per block,
//   shared 4x across wm-waves (L1-resident), L2/L3-resident across blocks.
// Correctness: all state is wave-private registers; ping-pong sets have
//   static names (rule 20); tail prefetch wraps &63 (dead data, valid mem).
// C/D layout (m74/m101, HW-verified): col = lane&31,
//   row = (reg&3) + 8*(reg>>2) + 4*(lane>>5).
// ---------------------------------------------------------------------------
__global__ __launch_bounds__(512, 2) void lstm_fused_kernel(
    const float* __restrict__ Cp, const ushort* __restrict__ Wt2,
    const ushort* __restrict__ Abf2,
    const float* __restrict__ bf_, const float* __restrict__ bi_,
    const float* __restrict__ bo_, const float* __restrict__ bc_,
    float* __restrict__ out) {
  const int bid = blockIdx.x;
  const int wg  = (bid & 7) * 64 + (bid >> 3);   // bijective, 512 % 8 == 0
  const int b0  = (wg >> 4) * BM;                // 32 M-tiles
  const int n0g = (wg & 15) * 64;                // 16 N-tiles (64 cols/gate)

  const int tid = threadIdx.x;
  const int ln  = tid & 63;
  const int wv  = tid >> 6;
  const int wm  = wv >> 1, wn = wv & 1;

  floatx16 acc[2][4];
#pragma unroll
  for (int m = 0; m < 2; ++m)
#pragma unroll
    for (int j = 0; j < 4; ++j)
#pragma unroll
      for (int e = 0; e < 16; ++e) acc[m][j][e] = 0.f;

  // ---- direct-load bases ----
  const char* Ab = (const char*)Abf2;
  const char* Wb = (const char*)Wt2;
  // A byte = aG + kt*524288 + ks*262144 + mt*512
  const unsigned aG = (unsigned)(ln >> 5) * 131072u +
                      (unsigned)(b0 + wm * 64 + (ln & 31)) * 16u;
  // W byte = wG + kt*262144 + ks*131072 + g*16384
  const unsigned wG = (unsigned)(ln >> 5) * 65536u +
                      (unsigned)(n0g + wn * 32 + (ln & 31)) * 16u;

  short8 aFA[2][2], aFB[2][2];   // [mt][ks]
  short8 bFA[4][2], bFB[4][2];   // [gate][ks]
#define LOADA(AF, kta)                                                        \
  do {                                                                        \
    _Pragma("unroll")                                                         \
    for (int mt_ = 0; mt_ < 2; ++mt_)                                         \
      _Pragma("unroll")                                                       \
      for (int ks_ = 0; ks_ < 2; ++ks_)                                       \
        AF[mt_][ks_] = *(const short8*)(Ab + (aG + (unsigned)(kta) +          \
                         (unsigned)ks_ * 262144u + (unsigned)mt_ * 512u));    \
  } while (0)
#define LOADB(BF, ktw)                                                        \
  do {                                                                        \
    _Pragma("unroll")                                                         \
    for (int g_ = 0; g_ < 4; ++g_)                                            \
      _Pragma("unroll")                                                       \
      for (int ks_ = 0; ks_ < 2; ++ks_)                                       \
        BF[g_][ks_] = *(const short8*)(Wb + (wG + (unsigned)(ktw) +           \
                         (unsigned)ks_ * 131072u + (unsigned)g_ * 16384u));   \
  } while (0)
#define MFALL(AF, BF)                                                         \
  do {                                                                        \
    _Pragma("unroll")                                                         \
    for (int ks_ = 0; ks_ < 2; ++ks_)                                         \
      _Pragma("unroll")                                                       \
      for (int mt_ = 0; mt_ < 2; ++mt_)                                       \
        _Pragma("unroll")                                                     \
        for (int g_ = 0; g_ < 4; ++g_)                                        \
          acc[mt_][g_] = __builtin_amdgcn_mfma_f32_32x32x16_bf16(             \
              AF[mt_][ks_], BF[g_][ks_], acc[mt_][g_], 0, 0, 0);              \
  } while (0)

  // ---- prologue: tile 0 into set A ----
  LOADA(aFA, 0);
  LOADB(bFA, 0);

#pragma unroll 1
  for (int it = 0; it < NKT / 2; ++it) {
    // window 2it: prefetch tile 2it+1 into set B; consume set A (tile 2it)
    {
      const unsigned ka = (unsigned)((2 * it + 1) & 63) * 524288u;
      const unsigned kw = (unsigned)((2 * it + 1) & 63) * 262144u;
      LOADA(aFB, ka);
      LOADB(bFB, kw);
      MFALL(aFA, bFA);
    }
    // window 2it+1: prefetch tile 2it+2 into set A; consume set B
    {
      const unsigned ka = (unsigned)((2 * it + 2) & 63) * 524288u;
      const unsigned kw = (unsigned)((2 * it + 2) & 63) * 262144u;
      LOADA(aFA, ka);
      LOADB(bFA, kw);
      MFALL(aFB, bFB);
    }
  }

  // ---- epilogue: acc[mt][gate]; col = ln&31, row per m74/m101 ----
  const int n = n0g + wn * 32 + (ln & 31);
  const float vbf = bf_[n], vbi = bi_[n], vbo = bo_[n], vbc = bc_[n];
  const int h2 = (ln >> 5) * 4;
  float* outh = out;
  float* outC = out + (size_t)B_SZ * H_SZ;
#pragma unroll
  for (int mt = 0; mt < 2; ++mt) {
#pragma unroll
    for (int reg = 0; reg < 16; ++reg) {
      int row = b0 + wm * 64 + mt * 32 + (reg & 3) + 8 * (reg >> 2) + h2;
      float fg = sigmoidf_(acc[mt][0][reg] + vbf);
      float ig = sigmoidf_(acc[mt][1][reg] + vbi);
      float og = sigmoidf_(acc[mt][2][reg] + vbo);
      float cg = tanhf_  (acc[mt][3][reg] + vbc);
      float cp = Cp[(size_t)row * H_SZ + n];
      float Ct = fg * cp + ig * cg;
      float ht = og * tanhf_(Ct);
      outh[(size_t)row * H_SZ + n] = ht;
      outC[(size_t)row * H_SZ + n] = Ct;
    }
  }
#undef LOADA
#undef LOADB
#undef MFALL
}

extern "C" void kernel_launch(void* const* d_in, const int* in_sizes, int n_in,
                              void* d_out, int out_size, void* d_ws, size_t ws_size,
                              hipStream_t stream) {
  const float* x  = (const float*)d_in[0];
  const float* hp = (const float*)d_in[1];
  const float* Cp = (const float*)d_in[2];
  const float* Wf = (const float*)d_in[3];
  const float* bf = (const float*)d_in[4];
  const float* Wi = (const float*)d_in[5];
  const float* bi = (const float*)d_in[6];
  const float* Wc = (const float*)d_in[7];
  const float* bc = (const float*)d_in[8];
  const float* Wo = (const float*)d_in[9];
  const float* bo = (const float*)d_in[10];

  ushort* Wt2  = (ushort*)d_ws;                          // 16 MiB, k-major
  ushort* Abf2 = (ushort*)((char*)d_ws + (16u << 20));   // 32 MiB, k-major

  dim3 gridW(16, 32, 4);          // (n-tiles, k-tiles, gates)
  convert_w2_kernel<<<gridW, 256, 0, stream>>>(Wf, Wi, Wo, Wc, Wt2);
  dim3 gridA(32, 128);            // (k-tiles, row-tiles)
  convert_a2_kernel<<<gridA, 256, 0, stream>>>(x, hp, Abf2);

  lstm_fused_kernel<<<512, 512, 0, stream>>>(Cp, Wt2, Abf2,
                                             bf, bi, bo, bc, (float*)d_out);
}

// Round 17
// 156.553 us; speedup vs baseline: 1.3737x; 1.3737x over previous
//
#include <hip/hip_runtime.h>
#include <hip/hip_bf16.h>

#define B_SZ 8192
#define IH   2048
#define H_SZ 1024
#define BM   256            // rows per block
#define BK   64             // K per tile
#define NT   (IH / BK)      // 32 K-tiles
#define NI   (NT / 2)       // 16 iterations, 2 K-tiles each
#define DBUF 65536          // one dbuf: A [256][128B] + W [256][128B]
#define WOFF 32768          // W region offset inside a dbuf

typedef __attribute__((ext_vector_type(8))) short  short8;
typedef __attribute__((ext_vector_type(4))) float  floatx4;

static __device__ __forceinline__ ushort f2bf(float f) {
  union { float f; unsigned u; } v; v.f = f;
  unsigned u = v.u;
  u += 0x7fffu + ((u >> 16) & 1u);   // RNE
  return (ushort)(u >> 16);
}
static __device__ __forceinline__ float sigmoidf_(float x) {
  return 1.0f / (1.0f + __expf(-x));
}
static __device__ __forceinline__ float tanhf_(float x) {
  float ax = fabsf(x);
  float e = __expf(-2.0f * ax);
  float t = (1.0f - e) / (1.0f + e);
  return copysignf(t, x);
}
static __device__ __forceinline__ void gload_lds16(const void* gsrc, void* ldst) {
  __builtin_amdgcn_global_load_lds(
      (__attribute__((address_space(1))) const void*)gsrc,
      (__attribute__((address_space(3))) void*)ldst, 16, 0, 0);
}

// ---------------------------------------------------------------------------
// Pre-pass 1: W[k][n] fp32 -> Wt[g][n][k] bf16 (K-contiguous for MFMA B-frag)
// ---------------------------------------------------------------------------
__global__ __launch_bounds__(256) void convert_w_kernel(
    const float* __restrict__ Wf, const float* __restrict__ Wi,
    const float* __restrict__ Wo, const float* __restrict__ Wc,
    ushort* __restrict__ Wt) {
  __shared__ float tile[64][65];
  const int g  = blockIdx.z;
  const float* W = (g == 0) ? Wf : (g == 1) ? Wi : (g == 2) ? Wo : Wc;
  const int n0 = blockIdx.x * 64;
  const int k0 = blockIdx.y * 64;
  const int tid = threadIdx.x;
#pragma unroll
  for (int i = 0; i < 4; ++i) {
    int c = i * 256 + tid;
    int r = c >> 4, c4 = c & 15;
    float4 v = *(const float4*)(W + (size_t)(k0 + r) * H_SZ + n0 + c4 * 4);
    tile[r][c4 * 4 + 0] = v.x;
    tile[r][c4 * 4 + 1] = v.y;
    tile[r][c4 * 4 + 2] = v.z;
    tile[r][c4 * 4 + 3] = v.w;
  }
  __syncthreads();
  const int n  = tid >> 2;
  const int kc = (tid & 3) * 16;
  ushort o[16] __attribute__((aligned(16)));
#pragma unroll
  for (int e = 0; e < 16; ++e) o[e] = f2bf(tile[kc + e][n]);
  ushort* dst = Wt + ((size_t)g * H_SZ + n0 + n) * IH + k0 + kc;
  *(uint4*)(dst)     = *(uint4*)&o[0];
  *(uint4*)(dst + 8) = *(uint4*)&o[8];
}

// ---------------------------------------------------------------------------
// Pre-pass 2: A = [x | h_prev] fp32 -> Abf[8192][2048] bf16
// ---------------------------------------------------------------------------
__global__ __launch_bounds__(256) void convert_a_kernel(
    const float* __restrict__ x, const float* __restrict__ hp,
    ushort* __restrict__ Abf) {
  size_t idx = ((size_t)blockIdx.x * 256 + threadIdx.x) * 8;
  size_t row = idx >> 11;
  size_t col = idx & 2047;
  const float* src = (col < 1024) ? (x  + row * 1024 + col)
                                  : (hp + row * 1024 + (col - 1024));
  float4 v0 = *(const float4*)(src);
  float4 v1 = *(const float4*)(src + 4);
  ushort o[8] __attribute__((aligned(16)));
  o[0] = f2bf(v0.x); o[1] = f2bf(v0.y); o[2] = f2bf(v0.z); o[3] = f2bf(v0.w);
  o[4] = f2bf(v1.x); o[5] = f2bf(v1.y); o[6] = f2bf(v1.z); o[7] = f2bf(v1.w);
  *(uint4*)(Abf + idx) = *(uint4*)&o[0];
}

// ---------------------------------------------------------------------------
// Fused 4-gate GEMM + LSTM epilogue — r4's verified 8-phase skeleton with
// m201's WAVE-TILE ORIENTATION: 8 waves = 2M x 4N; per-wave output
// 128 rows x (4 gates x 16 cols). Each wave reads ONE A-half (aF 8 frags,
// 16 b128/K-tile) + a quarter-slice of W (bF 4 frags = 4 gates, 8 b128).
// Read mix per phase: 12/8/4/0 (m201's); MFQ quadrant = 4mf x 2j x 2k = 16.
// Gate-locality preserved: acc[mf][g], all four gates in the same lane/reg.
//
// BEST-MEASURED CONFIGURATION (r11: 147.5 us fused, MfmaUtil 40%, 0 bank
// conflicts). Terminal revert — 12 structural variants (8-phase, 4-phase,
// counted lgkm/vmcnt, window-pipelined, T19 interleave, 2 barrier groups,
// direct-A, 32x32 MFMA, zero-LDS) all land 147-163 us: the plain-HIP
// 2-barrier-class ceiling (~930 TF here; guide m97-class ~900-950).
//
// Stage slots: P1{d1.W1} P2{d0.W0} P3{d0.A0} P4{d0.A1} P5{d0.W1} P6{d1.W0}
// P7{d1.A0} P8{d1.A1}; VMC(6) at P4/P8; LGKM0 before each MFQ; row-swizzle
// byte^=(row&7)<<4 via pre-swizzled global source (rule 21).
// ---------------------------------------------------------------------------
__global__ __launch_bounds__(512, 2) void lstm_fused_kernel(
    const float* __restrict__ Cp, const ushort* __restrict__ Wt,
    const ushort* __restrict__ Abf,
    const float* __restrict__ bf_, const float* __restrict__ bi_,
    const float* __restrict__ bo_, const float* __restrict__ bc_,
    float* __restrict__ out) {
  __shared__ char lds[2 * DBUF];   // 128 KiB

  const int bid = blockIdx.x;
  const int wg  = (bid & 7) * 64 + (bid >> 3);   // bijective, 512 % 8 == 0
  const int b0  = (wg >> 4) * BM;                // 32 M-tiles
  const int n0g = (wg & 15) * 64;                // 16 N-tiles (64 cols/gate)

  const int tid = threadIdx.x;
  const int ln  = tid & 63;
  const int wv  = tid >> 6;
  const int wm  = wv >> 2;        // 2 M-groups (128 rows each)
  const int wn  = wv & 3;         // 4 N-groups (16 cols/gate each)

  floatx4 acc[8][4];              // [mf][gate]
#pragma unroll
  for (int m = 0; m < 8; ++m)
#pragma unroll
    for (int j = 0; j < 4; ++j) acc[m][j] = {0.f, 0.f, 0.f, 0.f};

  // ---- pinned ds_read bases ----
  const int sw  = (ln & 7) << 4;
  const int kb0 = (((ln >> 4) << 4)) ^ sw;
  const int kb1 = (64 + ((ln >> 4) << 4)) ^ sw;
  const int aR  = (wm * 128 + (ln & 15)) * 128;        // A-half per wm
  const int bR  = WOFF + (wn * 16 + (ln & 15)) * 128;  // gate stride = imm
  int aB0[2], aB1[2], bB0[2], bB1[2];
#pragma unroll
  for (int d = 0; d < 2; ++d) {
    aB0[d] = d * DBUF + aR + kb0;  aB1[d] = d * DBUF + aR + kb1;
    bB0[d] = d * DBUF + bR + kb0;  bB1[d] = d * DBUF + bR + kb1;
  }

  // ---- stage constants (32-bit offsets) ----
  const unsigned kcsw = ((tid & 7) * 16) ^ (((tid >> 3) & 7) << 4);
  const char*  AbfB = (const char*)Abf;
  const char*  WtB  = (const char*)Wt;
  unsigned aoff[2];
#pragma unroll
  for (int i = 0; i < 2; ++i)
    aoff[i] = ((unsigned)(b0 + i * 64 + (tid >> 3)) << 12) + kcsw;
  unsigned woff[2][2];
#pragma unroll
  for (int h = 0; h < 2; ++h)
#pragma unroll
    for (int i = 0; i < 2; ++i) {
      int nrt  = h * 128 + i * 64 + (tid >> 3);
      int g    = nrt >> 6, nloc = nrt & 63;
      woff[h][i] = ((unsigned)(g * H_SZ + n0g + nloc) << 12) + kcsw;
    }
  int dsto[2];
#pragma unroll
  for (int i = 0; i < 2; ++i) dsto[i] = (i * 512 + wv * 64) * 16;

#define STAGE_A(db, ktb, h)                                                   \
  do {                                                                        \
    gload_lds16(AbfB + (aoff[0] + ((unsigned)(h) << 19) + (unsigned)(ktb)),   \
                lds + (db) + (h) * 16384 + dsto[0]);                          \
    gload_lds16(AbfB + (aoff[1] + ((unsigned)(h) << 19) + (unsigned)(ktb)),   \
                lds + (db) + (h) * 16384 + dsto[1]);                          \
  } while (0)
#define STAGE_W(db, ktb, h)                                                   \
  do {                                                                        \
    gload_lds16(WtB + (woff[h][0] + (unsigned)(ktb)),                         \
                lds + (db) + WOFF + (h) * 16384 + dsto[0]);                   \
    gload_lds16(WtB + (woff[h][1] + (unsigned)(ktb)),                         \
                lds + (db) + WOFF + (h) * 16384 + dsto[1]);                   \
  } while (0)

  short8 aF[8][2];
  short8 bF[4][2];
#define RD_A(dbi, mf)                                                         \
  do {                                                                        \
    aF[mf][0] = *(const short8*)(lds + aB0[dbi] + (mf) * 2048);               \
    aF[mf][1] = *(const short8*)(lds + aB1[dbi] + (mf) * 2048);               \
  } while (0)
#define RD_B(dbi, j)                                                          \
  do {                                                                        \
    bF[j][0] = *(const short8*)(lds + bB0[dbi] + (j) * 8192);                 \
    bF[j][1] = *(const short8*)(lds + bB1[dbi] + (j) * 8192);                 \
  } while (0)
// quadrant (mh, jh): mf 4mh..4mh+3, j 2jh..2jh+1, k 0..1 -> 16 MFMA
#define MFQ(mh, jh)                                                           \
  do {                                                                        \
    __builtin_amdgcn_s_setprio(1);                                            \
    _Pragma("unroll")                                                         \
    for (int k_ = 0; k_ < 2; ++k_)                                            \
      _Pragma("unroll")                                                       \
      for (int mf_ = 4 * (mh); mf_ < 4 * (mh) + 4; ++mf_)                     \
        _Pragma("unroll")                                                     \
        for (int j_ = 2 * (jh); j_ < 2 * (jh) + 2; ++j_)                      \
          acc[mf_][j_] = __builtin_amdgcn_mfma_f32_16x16x32_bf16(             \
              aF[mf_][k_], bF[j_][k_], acc[mf_][j_], 0, 0, 0);                \
    __builtin_amdgcn_s_setprio(0);                                            \
  } while (0)
#define BAR   __builtin_amdgcn_s_barrier()
#define LGKM0                                                                 \
  do {                                                                        \
    asm volatile("s_waitcnt lgkmcnt(0)" ::: "memory");                        \
    __builtin_amdgcn_sched_barrier(0);                                        \
  } while (0)
#define VMC6  asm volatile("s_waitcnt vmcnt(6)" ::: "memory")

  // ---- prologue (r4-identical) ----
  STAGE_W(0, 0, 0); STAGE_A(0, 0, 0); STAGE_A(0, 0, 1); STAGE_W(0, 0, 1);
  STAGE_W(DBUF, 128, 0); STAGE_A(DBUF, 128, 0); STAGE_A(DBUF, 128, 1);
  VMC6;
  BAR;

#pragma unroll 1
  for (int it = 0; it < NI; ++it) {
    const int kt1b  = (2 * it + 1) * 128;
    const int ktn0b = ((2 * it + 2) & 31) * 128;
    const int ktn1b = ((2 * it + 3) & 31) * 128;
    // P1: aF0-3 + bF0-1 (12 reads); stage d1.W1@2i+1
    RD_A(0, 0); RD_A(0, 1); RD_A(0, 2); RD_A(0, 3);
    RD_B(0, 0); RD_B(0, 1);
    STAGE_W(DBUF, kt1b, 1);
    BAR; LGKM0; MFQ(0, 0); BAR;
    // P2: aF4-7 (8 reads); stage d0.W0@2i+2
    RD_A(0, 4); RD_A(0, 5); RD_A(0, 6); RD_A(0, 7);
    STAGE_W(0, ktn0b, 0);
    BAR; LGKM0; MFQ(1, 0); BAR;
    // P3: bF2-3 (4 reads); stage d0.A0
    RD_B(0, 2); RD_B(0, 3);
    STAGE_A(0, ktn0b, 0);
    BAR; LGKM0; MFQ(0, 1); BAR;
    // P4: no reads; stage d0.A1; vmcnt(6) => d1 fully landed
    STAGE_A(0, ktn0b, 1);
    BAR; LGKM0; MFQ(1, 1);
    VMC6; BAR;
    // P5-P8: mirror on dbuf1
    RD_A(1, 0); RD_A(1, 1); RD_A(1, 2); RD_A(1, 3);
    RD_B(1, 0); RD_B(1, 1);
    STAGE_W(0, ktn0b, 1);
    BAR; LGKM0; MFQ(0, 0); BAR;
    RD_A(1, 4); RD_A(1, 5); RD_A(1, 6); RD_A(1, 7);
    STAGE_W(DBUF, ktn1b, 0);
    BAR; LGKM0; MFQ(1, 0); BAR;
    RD_B(1, 2); RD_B(1, 3);
    STAGE_A(DBUF, ktn1b, 0);
    BAR; LGKM0; MFQ(0, 1); BAR;
    STAGE_A(DBUF, ktn1b, 1);
    BAR; LGKM0; MFQ(1, 1);
    VMC6; BAR;
  }

  // ---- epilogue: acc[mf][g]; all 4 gates in same lane/reg ----
  const int colq = ln & 15;
  const int rq   = ln >> 4;
  float* outh = out;
  float* outC = out + (size_t)B_SZ * H_SZ;
  const int n = n0g + wn * 16 + colq;
  const float vbf = bf_[n], vbi = bi_[n], vbo = bo_[n], vbc = bc_[n];
#pragma unroll
  for (int mf = 0; mf < 8; ++mf) {
#pragma unroll
    for (int r = 0; r < 4; ++r) {
      int row = b0 + wm * 128 + mf * 16 + rq * 4 + r;
      float fg = sigmoidf_(acc[mf][0][r] + vbf);
      float ig = sigmoidf_(acc[mf][1][r] + vbi);
      float og = sigmoidf_(acc[mf][2][r] + vbo);
      float cg = tanhf_  (acc[mf][3][r] + vbc);
      float cp = Cp[(size_t)row * H_SZ + n];
      float Ct = fg * cp + ig * cg;
      float ht = og * tanhf_(Ct);
      outh[(size_t)row * H_SZ + n] = ht;
      outC[(size_t)row * H_SZ + n] = Ct;
    }
  }
#undef STAGE_A
#undef STAGE_W
#undef RD_A
#undef RD_B
#undef MFQ
#undef BAR
#undef LGKM0
#undef VMC6
}

extern "C" void kernel_launch(void* const* d_in, const int* in_sizes, int n_in,
                              void* d_out, int out_size, void* d_ws, size_t ws_size,
                              hipStream_t stream) {
  const float* x  = (const float*)d_in[0];
  const float* hp = (const float*)d_in[1];
  const float* Cp = (const float*)d_in[2];
  const float* Wf = (const float*)d_in[3];
  const float* bf = (const float*)d_in[4];
  const float* Wi = (const float*)d_in[5];
  const float* bi = (const float*)d_in[6];
  const float* Wc = (const float*)d_in[7];
  const float* bc = (const float*)d_in[8];
  const float* Wo = (const float*)d_in[9];
  const float* bo = (const float*)d_in[10];

  ushort* Wt  = (ushort*)d_ws;                           // 16 MiB
  ushort* Abf = (ushort*)((char*)d_ws + (16u << 20));    // 32 MiB

  dim3 gridT(16, 32, 4);
  convert_w_kernel<<<gridT, 256, 0, stream>>>(Wf, Wi, Wo, Wc, Wt);
  convert_a_kernel<<<8192, 256, 0, stream>>>(x, hp, Abf);

  lstm_fused_kernel<<<512, 512, 0, stream>>>(Cp, Wt, Abf,
                                             bf, bi, bo, bc, (float*)d_out);
}